// Round 2
// baseline (52.427 us; speedup 1.0000x reference)
//
#include <hip/hip_runtime.h>

typedef float f4 __attribute__((ext_vector_type(4)));

#define INV_SQRT2 0.70710678118654752440f

// Fused FrequencyLayer:
//  - 3-level Haar DWT/IDWT along S is local within blocks of 8 sequence
//    positions, so everything up to the pre-LN activation is an 8-point
//    stencil per (b, h).
//  - Block = one (b, s-block of 8) x all H=1024. Thread t owns h=4t..4t+3.
//  - LayerNorm over H done with wave shuffle reduce + 4-wave LDS combine.
//  - Input/output streams are non-temporal (zero reuse; together they equal
//    the whole 256 MiB L3). Weights stay on the cached path (heavy reuse).
__global__ __launch_bounds__(256) void freq_layer_fused(
    const float* __restrict__ in,        // [64, 512, 1024]
    const float* __restrict__ ww0,       // [256, 1024]
    const float* __restrict__ ww1,       // [128, 1024]
    const float* __restrict__ ww2,       // [64, 1024]
    const float* __restrict__ srt,       // [1024]
    const float* __restrict__ sqrt_beta, // [1024]
    const float* __restrict__ ln_w,      // [1024]
    const float* __restrict__ ln_b,      // [1024]
    float* __restrict__ out)             // [64, 512, 1024]
{
    constexpr int H = 1024;
    constexpr int S = 512;
    constexpr float c = INV_SQRT2;

    const int t  = threadIdx.x;        // 0..255
    const int k  = blockIdx.x & 63;    // s-block index (8 rows each)
    const int b  = blockIdx.x >> 6;    // batch
    const int h0 = t << 2;             // this thread's first h

    const size_t rowbase = ((size_t)b * S + (size_t)(k << 3)) * H + (size_t)h0;

    // ---- load the 8 x 4 input stencil (coalesced float4 per row, nt) ----
    f4 y[8];
    #pragma unroll
    for (int j = 0; j < 8; ++j)
        y[j] = __builtin_nontemporal_load(
                   reinterpret_cast<const f4*>(in + rowbase + (size_t)j * H));

    // ---- per-h weights (cached path; reused by all 4096 blocks) ----
    f4 s2 = *reinterpret_cast<const f4*>(srt + h0);
    s2 *= s2;                                  // srt^2
    f4 b2 = *reinterpret_cast<const f4*>(sqrt_beta + h0);
    b2 *= b2;                                  // sqrt_beta^2

    f4 w0[4], w1[2], w2v;
    #pragma unroll
    for (int j = 0; j < 4; ++j)
        w0[j] = *reinterpret_cast<const f4*>(ww0 + (size_t)((k << 2) + j) * H + h0) * s2;
    #pragma unroll
    for (int j = 0; j < 2; ++j)
        w1[j] = *reinterpret_cast<const f4*>(ww1 + (size_t)((k << 1) + j) * H + h0) * s2;
    w2v = *reinterpret_cast<const f4*>(ww2 + (size_t)k * H + h0) * s2;

    // ---- DWT -> scale -> IDWT -> seq_emb + residual, per h column ----
    f4 xo[8];
    float ssum[8], ssq[8];
    #pragma unroll
    for (int j = 0; j < 8; ++j) { ssum[j] = 0.f; ssq[j] = 0.f; }

    #pragma unroll
    for (int hh = 0; hh < 4; ++hh) {
        float yc[8];
        #pragma unroll
        for (int j = 0; j < 8; ++j) yc[j] = y[j][hh];

        // forward Haar (3 levels), with the scaling folded into the details
        const float a0 = (yc[0] + yc[1]) * c;
        const float a1 = (yc[2] + yc[3]) * c;
        const float a2 = (yc[4] + yc[5]) * c;
        const float a3 = (yc[6] + yc[7]) * c;
        const float d10 = (yc[0] - yc[1]) * c * w0[0][hh];
        const float d11 = (yc[2] - yc[3]) * c * w0[1][hh];
        const float d12 = (yc[4] - yc[5]) * c * w0[2][hh];
        const float d13 = (yc[6] - yc[7]) * c * w0[3][hh];
        const float bb0 = (a0 + a1) * c;
        const float bb1 = (a2 + a3) * c;
        const float d20 = (a0 - a1) * c * w1[0][hh];
        const float d21 = (a2 - a3) * c * w1[1][hh];
        const float cc  = (bb0 + bb1) * c;
        const float d3  = (bb0 - bb1) * c * w2v[hh];

        // inverse Haar
        const float b0p = (cc + d3) * c;
        const float b1p = (cc - d3) * c;
        const float a0p = (b0p + d20) * c;
        const float a1p = (b0p - d20) * c;
        const float a2p = (b1p + d21) * c;
        const float a3p = (b1p - d21) * c;
        float lp[8];
        lp[0] = (a0p + d10) * c;
        lp[1] = (a0p - d10) * c;
        lp[2] = (a1p + d11) * c;
        lp[3] = (a1p - d11) * c;
        lp[4] = (a2p + d12) * c;
        lp[5] = (a2p - d12) * c;
        lp[6] = (a3p + d13) * c;
        lp[7] = (a3p - d13) * c;

        const float bb = b2[hh];
        #pragma unroll
        for (int j = 0; j < 8; ++j) {
            const float hpv = yc[j] - lp[j];            // high_pass
            const float v   = lp[j] + bb * hpv + yc[j]; // seq_emb + residual
            xo[j][hh] = v;
            ssum[j] += v;
            ssq[j]  += v * v;
        }
    }

    // ---- LayerNorm reductions: 8 rows, each over 1024 h ----
    #pragma unroll
    for (int m = 1; m < 64; m <<= 1) {
        #pragma unroll
        for (int j = 0; j < 8; ++j) {
            ssum[j] += __shfl_xor(ssum[j], m, 64);
            ssq[j]  += __shfl_xor(ssq[j],  m, 64);
        }
    }

    __shared__ float red[4][16];
    const int wave = t >> 6;
    if ((t & 63) == 0) {
        #pragma unroll
        for (int j = 0; j < 8; ++j) {
            red[wave][j]     = ssum[j];
            red[wave][8 + j] = ssq[j];
        }
    }
    __syncthreads();

    const f4 lw = *reinterpret_cast<const f4*>(ln_w + h0);
    const f4 lb = *reinterpret_cast<const f4*>(ln_b + h0);

    #pragma unroll
    for (int j = 0; j < 8; ++j) {
        const float Sj = red[0][j] + red[1][j] + red[2][j] + red[3][j];
        const float Qj = red[0][8 + j] + red[1][8 + j] + red[2][8 + j] + red[3][8 + j];
        const float u   = Sj * (1.0f / 1024.0f);
        const float var = Qj * (1.0f / 1024.0f) - u * u;
        const float r   = rsqrtf(var + 1e-12f);
        f4 o;
        #pragma unroll
        for (int hh = 0; hh < 4; ++hh)
            o[hh] = lw[hh] * ((xo[j][hh] - u) * r) + lb[hh];
        __builtin_nontemporal_store(
            o, reinterpret_cast<f4*>(out + rowbase + (size_t)j * H));
    }
}

extern "C" void kernel_launch(void* const* d_in, const int* in_sizes, int n_in,
                              void* d_out, int out_size, void* d_ws, size_t ws_size,
                              hipStream_t stream) {
    const float* in   = (const float*)d_in[0];
    const float* ww0  = (const float*)d_in[1];
    const float* ww1  = (const float*)d_in[2];
    const float* ww2  = (const float*)d_in[3];
    const float* srt  = (const float*)d_in[4];
    const float* sb   = (const float*)d_in[5];
    const float* lnw  = (const float*)d_in[6];
    const float* lnb  = (const float*)d_in[7];
    float* out = (float*)d_out;

    // grid = B * (S/8) = 64 * 64
    freq_layer_fused<<<dim3(64 * 64), dim3(256), 0, stream>>>(
        in, ww0, ww1, ww2, srt, sb, lnw, lnb, out);
}

// Round 3
// 47.095 us; speedup vs baseline: 1.1132x; 1.1132x over previous
//
#include <hip/hip_runtime.h>

typedef float f4 __attribute__((ext_vector_type(4)));

#define INV_SQRT2 0.70710678118654752440f

// Fused FrequencyLayer:
//  - 3-level Haar DWT/IDWT along S is local within blocks of 8 sequence
//    positions, so everything up to the pre-LN activation is an 8-point
//    stencil per (b, h).
//  - Block = one (b, s-block of 8) x all H=1024. Thread t owns h=4t..4t+3.
//  - LayerNorm over H done with wave shuffle reduce + 4-wave LDS combine.
//  - R2 lesson: non-temporal load/store hints REGRESS on gfx950 (47->52us);
//    plain cached loads/stores. This round: activation overwritten into y[]
//    in place (drops the separate xo[8] array, ~32 VGPRs) to get under the
//    128-VGPR occupancy cliff.
__global__ __launch_bounds__(256) void freq_layer_fused(
    const float* __restrict__ in,        // [64, 512, 1024]
    const float* __restrict__ ww0,       // [256, 1024]
    const float* __restrict__ ww1,       // [128, 1024]
    const float* __restrict__ ww2,       // [64, 1024]
    const float* __restrict__ srt,       // [1024]
    const float* __restrict__ sqrt_beta, // [1024]
    const float* __restrict__ ln_w,      // [1024]
    const float* __restrict__ ln_b,      // [1024]
    float* __restrict__ out)             // [64, 512, 1024]
{
    constexpr int H = 1024;
    constexpr int S = 512;
    constexpr float c = INV_SQRT2;

    const int t  = threadIdx.x;        // 0..255
    const int k  = blockIdx.x & 63;    // s-block index (8 rows each)
    const int b  = blockIdx.x >> 6;    // batch
    const int h0 = t << 2;             // this thread's first h

    const size_t rowbase = ((size_t)b * S + (size_t)(k << 3)) * H + (size_t)h0;

    // ---- load the 8 x 4 input stencil (coalesced float4 per row) ----
    f4 y[8];
    #pragma unroll
    for (int j = 0; j < 8; ++j)
        y[j] = *reinterpret_cast<const f4*>(in + rowbase + (size_t)j * H);

    // ---- per-h weights (cached path; reused by all 4096 blocks) ----
    f4 s2 = *reinterpret_cast<const f4*>(srt + h0);
    s2 *= s2;                                  // srt^2
    f4 b2 = *reinterpret_cast<const f4*>(sqrt_beta + h0);
    b2 *= b2;                                  // sqrt_beta^2

    f4 w0[4], w1[2], w2v;
    #pragma unroll
    for (int j = 0; j < 4; ++j)
        w0[j] = *reinterpret_cast<const f4*>(ww0 + (size_t)((k << 2) + j) * H + h0) * s2;
    #pragma unroll
    for (int j = 0; j < 2; ++j)
        w1[j] = *reinterpret_cast<const f4*>(ww1 + (size_t)((k << 1) + j) * H + h0) * s2;
    w2v = *reinterpret_cast<const f4*>(ww2 + (size_t)k * H + h0) * s2;

    // ---- DWT -> scale -> IDWT -> seq_emb + residual, per h column ----
    // Result is written back into y[j][hh] in place (yc holds the column
    // copy, so the overwrite is hazard-free). Saves 8 f4 of live registers.
    float ssum[8], ssq[8];
    #pragma unroll
    for (int j = 0; j < 8; ++j) { ssum[j] = 0.f; ssq[j] = 0.f; }

    #pragma unroll
    for (int hh = 0; hh < 4; ++hh) {
        float yc[8];
        #pragma unroll
        for (int j = 0; j < 8; ++j) yc[j] = y[j][hh];

        // forward Haar (3 levels), with the scaling folded into the details
        const float a0 = (yc[0] + yc[1]) * c;
        const float a1 = (yc[2] + yc[3]) * c;
        const float a2 = (yc[4] + yc[5]) * c;
        const float a3 = (yc[6] + yc[7]) * c;
        const float d10 = (yc[0] - yc[1]) * c * w0[0][hh];
        const float d11 = (yc[2] - yc[3]) * c * w0[1][hh];
        const float d12 = (yc[4] - yc[5]) * c * w0[2][hh];
        const float d13 = (yc[6] - yc[7]) * c * w0[3][hh];
        const float bb0 = (a0 + a1) * c;
        const float bb1 = (a2 + a3) * c;
        const float d20 = (a0 - a1) * c * w1[0][hh];
        const float d21 = (a2 - a3) * c * w1[1][hh];
        const float cc  = (bb0 + bb1) * c;
        const float d3  = (bb0 - bb1) * c * w2v[hh];

        // inverse Haar
        const float b0p = (cc + d3) * c;
        const float b1p = (cc - d3) * c;
        const float a0p = (b0p + d20) * c;
        const float a1p = (b0p - d20) * c;
        const float a2p = (b1p + d21) * c;
        const float a3p = (b1p - d21) * c;
        float lp[8];
        lp[0] = (a0p + d10) * c;
        lp[1] = (a0p - d10) * c;
        lp[2] = (a1p + d11) * c;
        lp[3] = (a1p - d11) * c;
        lp[4] = (a2p + d12) * c;
        lp[5] = (a2p - d12) * c;
        lp[6] = (a3p + d13) * c;
        lp[7] = (a3p - d13) * c;

        const float bb = b2[hh];
        #pragma unroll
        for (int j = 0; j < 8; ++j) {
            const float hpv = yc[j] - lp[j];            // high_pass
            const float v   = lp[j] + bb * hpv + yc[j]; // seq_emb + residual
            y[j][hh] = v;                               // in-place
            ssum[j] += v;
            ssq[j]  += v * v;
        }
    }

    // ---- LayerNorm reductions: 8 rows, each over 1024 h ----
    #pragma unroll
    for (int m = 1; m < 64; m <<= 1) {
        #pragma unroll
        for (int j = 0; j < 8; ++j) {
            ssum[j] += __shfl_xor(ssum[j], m, 64);
            ssq[j]  += __shfl_xor(ssq[j],  m, 64);
        }
    }

    __shared__ float red[4][16];
    const int wave = t >> 6;
    if ((t & 63) == 0) {
        #pragma unroll
        for (int j = 0; j < 8; ++j) {
            red[wave][j]     = ssum[j];
            red[wave][8 + j] = ssq[j];
        }
    }
    __syncthreads();

    const f4 lw = *reinterpret_cast<const f4*>(ln_w + h0);
    const f4 lb = *reinterpret_cast<const f4*>(ln_b + h0);

    #pragma unroll
    for (int j = 0; j < 8; ++j) {
        const float Sj = red[0][j] + red[1][j] + red[2][j] + red[3][j];
        const float Qj = red[0][8 + j] + red[1][8 + j] + red[2][8 + j] + red[3][8 + j];
        const float u   = Sj * (1.0f / 1024.0f);
        const float var = Qj * (1.0f / 1024.0f) - u * u;
        const float r   = rsqrtf(var + 1e-12f);
        f4 o;
        #pragma unroll
        for (int hh = 0; hh < 4; ++hh)
            o[hh] = lw[hh] * ((y[j][hh] - u) * r) + lb[hh];
        *reinterpret_cast<f4*>(out + rowbase + (size_t)j * H) = o;
    }
}

extern "C" void kernel_launch(void* const* d_in, const int* in_sizes, int n_in,
                              void* d_out, int out_size, void* d_ws, size_t ws_size,
                              hipStream_t stream) {
    const float* in   = (const float*)d_in[0];
    const float* ww0  = (const float*)d_in[1];
    const float* ww1  = (const float*)d_in[2];
    const float* ww2  = (const float*)d_in[3];
    const float* srt  = (const float*)d_in[4];
    const float* sb   = (const float*)d_in[5];
    const float* lnw  = (const float*)d_in[6];
    const float* lnb  = (const float*)d_in[7];
    float* out = (float*)d_out;

    // grid = B * (S/8) = 64 * 64
    freq_layer_fused<<<dim3(64 * 64), dim3(256), 0, stream>>>(
        in, ww0, ww1, ww2, srt, sb, lnw, lnb, out);
}